// Round 4
// baseline (184.369 us; speedup 1.0000x reference)
//
#include <hip/hip_runtime.h>
#include <hip/hip_bf16.h>
#include <math.h>

typedef __attribute__((ext_vector_type(4))) float f32x4;
typedef __attribute__((ext_vector_type(8))) short short8;
typedef __attribute__((ext_vector_type(4))) short short4v;

__device__ __forceinline__ short f2bf(float f) {
    union { __hip_bfloat16 h; short s; } u;
    u.h = __float2bfloat16(f);
    return u.s;
}

__device__ __forceinline__ f32x4 mfma16(short8 a, short8 b, f32x4 c) {
    return __builtin_amdgcn_mfma_f32_16x16x32_bf16(a, b, c, 0, 0, 0);
}

// ---------------- prep: fp32 -> bf16 convert ----------------
__global__ __launch_bounds__(256) void cvt_bf16(const float* __restrict__ in,
                                                short* __restrict__ out, int n) {
    int i = (blockIdx.x * 256 + threadIdx.x) * 8;
    if (i >= n) return;
    float4 a = *reinterpret_cast<const float4*>(in + i);
    float4 b = *reinterpret_cast<const float4*>(in + i + 4);
    short8 o;
    o[0] = f2bf(a.x); o[1] = f2bf(a.y); o[2] = f2bf(a.z); o[3] = f2bf(a.w);
    o[4] = f2bf(b.x); o[5] = f2bf(b.y); o[6] = f2bf(b.z); o[7] = f2bf(b.w);
    *reinterpret_cast<short8*>(out + i) = o;
}

// ---------------- prep: transpose fp32 [K][N] -> bf16 [N][K] ----------------
__global__ __launch_bounds__(256) void transpose_w(const float* __restrict__ W,
                                                   short* __restrict__ Wt,
                                                   int K, int N) {
    __shared__ float tile[64][68];
    const int k0 = blockIdx.x * 64;
    const int n0 = blockIdx.y * 64;
    const int tid = threadIdx.x;
    #pragma unroll
    for (int i = 0; i < 4; ++i) {
        int c = tid + i * 256;
        int r = c >> 4;
        int col4 = (c & 15) * 4;
        float4 v = *reinterpret_cast<const float4*>(W + (size_t)(k0 + r) * N + n0 + col4);
        tile[r][col4 + 0] = v.x; tile[r][col4 + 1] = v.y;
        tile[r][col4 + 2] = v.z; tile[r][col4 + 3] = v.w;
    }
    __syncthreads();
    #pragma unroll
    for (int i = 0; i < 4; ++i) {
        int c = tid + i * 256;
        int r2 = c >> 4;
        int col4 = (c & 15) * 4;
        short4v o;
        #pragma unroll
        for (int j = 0; j < 4; ++j) o[j] = f2bf(tile[col4 + j][r2]);
        *reinterpret_cast<short4v*>(Wt + (size_t)(n0 + r2) * K + k0 + col4) = o;
    }
}

// ---------------- GEMM: C[M,N] = A[M,K](bf16) * Bt[N,K](bf16)^T + bias ----------------
template<int MODE>
__global__ __launch_bounds__(256) void gemm_bt(const short* __restrict__ A,
                                               const short* __restrict__ Bt,
                                               const float* __restrict__ bias,
                                               void* __restrict__ C,
                                               short* __restrict__ vt,
                                               int M, int N, int K) {
    constexpr int BM = 128, BN = 128, BK = 64, LDP = BK + 8;
    __shared__ short As[BM * LDP];
    __shared__ short Bs[BN * LDP];
    const int tid = threadIdx.x;
    const int lane = tid & 63, wave = tid >> 6;
    const int bm = blockIdx.x * BM, bn = blockIdx.y * BN;
    const int wr = (wave >> 1) * 64, wc = (wave & 1) * 64;
    const int g = lane >> 4, l15 = lane & 15;

    f32x4 acc[4][4] = {};

    for (int k0 = 0; k0 < K; k0 += BK) {
        __syncthreads();
        #pragma unroll
        for (int i = 0; i < 4; ++i) {
            int c = tid + i * 256;
            int r = c >> 3;
            int col = (c & 7) * 8;
            *reinterpret_cast<short8*>(&As[r * LDP + col]) =
                *reinterpret_cast<const short8*>(A + (size_t)(bm + r) * K + k0 + col);
            *reinterpret_cast<short8*>(&Bs[r * LDP + col]) =
                *reinterpret_cast<const short8*>(Bt + (size_t)(bn + r) * K + k0 + col);
        }
        __syncthreads();
        #pragma unroll
        for (int kk = 0; kk < 2; ++kk) {
            short8 af[4], bfr[4];
            #pragma unroll
            for (int m = 0; m < 4; ++m)
                af[m] = *reinterpret_cast<const short8*>(&As[(wr + m * 16 + l15) * LDP + kk * 32 + g * 8]);
            #pragma unroll
            for (int n = 0; n < 4; ++n)
                bfr[n] = *reinterpret_cast<const short8*>(&Bs[(wc + n * 16 + l15) * LDP + kk * 32 + g * 8]);
            #pragma unroll
            for (int m = 0; m < 4; ++m)
                #pragma unroll
                for (int n = 0; n < 4; ++n)
                    acc[m][n] = mfma16(af[m], bfr[n], acc[m][n]);
        }
    }

    #pragma unroll
    for (int m = 0; m < 4; ++m)
        #pragma unroll
        for (int n = 0; n < 4; ++n) {
            int gc = bn + wc + n * 16 + l15;
            float bv = bias[gc];
            int gr0 = bm + wr + m * 16 + g * 4;
            if (MODE == 0) {
                #pragma unroll
                for (int r = 0; r < 4; ++r)
                    reinterpret_cast<float*>(C)[(size_t)(gr0 + r) * N + gc] = acc[m][n][r] + bv;
            } else {
                if (gc < 2048) {
                    float sc = (gc < 1024) ? 0.125f : 1.0f;
                    short* qkp = reinterpret_cast<short*>(C);
                    #pragma unroll
                    for (int r = 0; r < 4; ++r)
                        qkp[(size_t)(gr0 + r) * 2048 + gc] = f2bf((acc[m][n][r] + bv) * sc);
                } else {
                    int cv = gc - 2048;            // h*64 + d
                    int bb = gr0 >> 11;            // batch
                    int t0 = gr0 & 2047;           // time (multiple of 4)
                    short4v o;
                    #pragma unroll
                    for (int r = 0; r < 4; ++r) o[r] = f2bf(acc[m][n][r] + bv);
                    *reinterpret_cast<short4v*>(&vt[((size_t)(bb << 10) + cv) * 2048 + t0]) = o;
                }
            }
        }
}

// ---------------- flash attention (barrier-free, direct-L2) ----------------
// One wave per block; 32 q-rows per wave; K/V fragments read straight from
// global (L2-resident per XCD: 4 (b,h) groups x 512 KB = 2 MB < 4 MB).
// Row-sum of P comes from an extra MFMA against a ones-fragment (no shuffles).
// NOTE: P round-trip through LDS uses direct indexing off the shared base —
// NO __restrict__ — so the compiler sees the ds_write->ds_read dependence
// (round-3 restrict pointers let it reorder the reads -> NaN).

template<int NMAX, int KKMAX, bool MASK>
__device__ __forceinline__ void tile_step(const short* __restrict__ Kl,   // qk+baseK+l15*2048+g*8  (+kb rows)
                                          const short* __restrict__ Vl,   // vt+vbase+l15*2048+g*8  (+kb cols)
                                          short* Ps, int l15, int g,
                                          const short8 (&qf)[2][2],
                                          f32x4 (&oacc)[2][4],
                                          f32x4 (&lacc)[2],
                                          float (&mst)[2][4],
                                          int rowbase, int colbase,
                                          short8 ones) {
    // ---- S = (Q/8) K^T ----
    f32x4 sacc[2][NMAX + 1];
    #pragma unroll
    for (int m = 0; m < 2; ++m)
        #pragma unroll
        for (int n = 0; n <= NMAX; ++n) sacc[m][n] = f32x4{0.f, 0.f, 0.f, 0.f};
    __builtin_amdgcn_s_setprio(1);
    #pragma unroll
    for (int kk = 0; kk < 2; ++kk)
        #pragma unroll
        for (int n = 0; n <= NMAX; ++n) {
            short8 kf = *reinterpret_cast<const short8*>(Kl + (size_t)n * 16 * 2048 + kk * 32);
            sacc[0][n] = mfma16(qf[0][kk], kf, sacc[0][n]);
            sacc[1][n] = mfma16(qf[1][kk], kf, sacc[1][n]);
        }
    __builtin_amdgcn_s_setprio(0);

    // ---- prefetch V fragments (latency hides under softmax) ----
    short8 vf[KKMAX + 1][4];
    #pragma unroll
    for (int kk = 0; kk <= KKMAX; ++kk)
        #pragma unroll
        for (int nd = 0; nd < 4; ++nd)
            vf[kk][nd] = *reinterpret_cast<const short8*>(Vl + (size_t)nd * 16 * 2048 + kk * 32);

    // ---- causal mask (diag tile only) ----
    if (MASK) {
        #pragma unroll
        for (int m = 0; m < 2; ++m)
            #pragma unroll
            for (int n = 0; n <= NMAX; ++n)
                #pragma unroll
                for (int r = 0; r < 4; ++r) {
                    int row = rowbase + m * 16 + r;
                    int col = colbase + n * 16;
                    if (col > row) sacc[m][n][r] = -INFINITY;
                }
    }

    // ---- online softmax (max via 4 shuffles; sum deferred to MFMA-ones) ----
    #pragma unroll
    for (int m = 0; m < 2; ++m)
        #pragma unroll
        for (int r = 0; r < 4; ++r) {
            float rm = sacc[m][0][r];
            #pragma unroll
            for (int n = 1; n <= NMAX; ++n) rm = fmaxf(rm, sacc[m][n][r]);
            #pragma unroll
            for (int w = 1; w < 16; w <<= 1) rm = fmaxf(rm, __shfl_xor(rm, w));
            float mn = fmaxf(mst[m][r], rm);
            float corr = __expf(mst[m][r] - mn);
            mst[m][r] = mn;
            #pragma unroll
            for (int n = 0; n <= NMAX; ++n) {
                float p = __expf(sacc[m][n][r] - mn);
                Ps[(g * 4 + m * 16 + r) * 72 + n * 16 + l15] = f2bf(p);
            }
            lacc[m][r] *= corr;
            #pragma unroll
            for (int nd = 0; nd < 4; ++nd) oacc[m][nd][r] *= corr;
        }

    // ---- O += P V ;  l += P 1 ----
    __builtin_amdgcn_s_setprio(1);
    #pragma unroll
    for (int kk = 0; kk <= KKMAX; ++kk) {
        short8 pa0 = *reinterpret_cast<const short8*>(&Ps[l15 * 72 + kk * 32 + g * 8]);
        short8 pa1 = *reinterpret_cast<const short8*>(&Ps[(16 + l15) * 72 + kk * 32 + g * 8]);
        #pragma unroll
        for (int nd = 0; nd < 4; ++nd) {
            oacc[0][nd] = mfma16(pa0, vf[kk][nd], oacc[0][nd]);
            oacc[1][nd] = mfma16(pa1, vf[kk][nd], oacc[1][nd]);
        }
        lacc[0] = mfma16(pa0, ones, lacc[0]);
        lacc[1] = mfma16(pa1, ones, lacc[1]);
    }
    __builtin_amdgcn_s_setprio(0);
}

__global__ __launch_bounds__(64) void attn_kernel(const short* __restrict__ qk,
                                                  const short* __restrict__ vt,
                                                  short* __restrict__ yatt) {
    constexpr int T = 2048;
    __shared__ short Ps[32 * 72];      // wave-private P tile [32 q][64 kv], padded

    const int lane = threadIdx.x & 63;
    const int g = lane >> 4, l15 = lane & 15;

    // decode: XCD-grouped (b,h); heavy q-blocks dispatched first
    const int bid = blockIdx.x;        // 0..2047
    const int xcd = bid & 7;
    const int idx = bid >> 3;          // 0..255
    const int grp = xcd * 4 + (idx >> 6);
    const int h = grp & 15, b = grp >> 4;
    const int qt = 63 - (idx & 63);    // 0..63, heavy first
    const int qs = qt * 32;

    const size_t baseQ = (size_t)b * T * 2048 + (size_t)h * 64;
    const short* Kl = qk + baseQ + 1024 + (size_t)l15 * 2048 + g * 8;
    const short* Vl = vt + ((size_t)b * 1024 + (size_t)h * 64) * 2048 + (size_t)l15 * 2048 + g * 8;

    short8 ones;
    #pragma unroll
    for (int i = 0; i < 8; ++i) ones[i] = (short)0x3F80;   // bf16 1.0

    // Q fragments (pre-scaled by 1/8 at GEMM1 epilogue)
    short8 qf[2][2];
    #pragma unroll
    for (int m = 0; m < 2; ++m)
        #pragma unroll
        for (int kk = 0; kk < 2; ++kk)
            qf[m][kk] = *reinterpret_cast<const short8*>(
                qk + baseQ + (size_t)(qs + m * 16 + l15) * 2048 + kk * 32 + g * 8);

    f32x4 oacc[2][4] = {};
    f32x4 lacc[2] = {};
    float mst[2][4];
    #pragma unroll
    for (int m = 0; m < 2; ++m)
        #pragma unroll
        for (int r = 0; r < 4; ++r) mst[m][r] = -INFINITY;

    const int rowbase = qs + g * 4;
    int colbase = l15;
    const int jd = qt >> 1;

    const short* Klj = Kl;
    const short* Vlj = Vl;
    for (int j = 0; j < jd; ++j) {
        tile_step<3, 1, false>(Klj, Vlj, Ps, l15, g, qf, oacc, lacc, mst, rowbase, colbase, ones);
        Klj += 64 * 2048;
        Vlj += 64;
        colbase += 64;
    }
    if (qt & 1)
        tile_step<3, 1, true>(Klj, Vlj, Ps, l15, g, qf, oacc, lacc, mst, rowbase, colbase, ones);
    else
        tile_step<1, 0, true>(Klj, Vlj, Ps, l15, g, qf, oacc, lacc, mst, rowbase, colbase, ones);

    // epilogue: O / l
    #pragma unroll
    for (int m = 0; m < 2; ++m)
        #pragma unroll
        for (int r = 0; r < 4; ++r) {
            float rl = 1.0f / lacc[m][r];
            int row = qs + m * 16 + g * 4 + r;
            #pragma unroll
            for (int nd = 0; nd < 4; ++nd) {
                int col = nd * 16 + l15;
                yatt[((size_t)b * T + row) * 1024 + h * 64 + col] = f2bf(oacc[m][nd][r] * rl);
            }
        }
}

// ---------------- launch ----------------
extern "C" void kernel_launch(void* const* d_in, const int* in_sizes, int n_in,
                              void* d_out, int out_size, void* d_ws, size_t ws_size,
                              hipStream_t stream) {
    constexpr int B = 2, T = 2048, C = 1024;
    constexpr int M = B * T;       // 4096
    constexpr int N1 = 3 * C;      // 3072
    constexpr int K = C;           // 1024

    const float* x      = (const float*)d_in[0];
    const float* W_attn = (const float*)d_in[1];
    const float* b_attn = (const float*)d_in[2];
    const float* W_proj = (const float*)d_in[3];
    const float* b_proj = (const float*)d_in[4];
    float* out = (float*)d_out;

    char* ws = (char*)d_ws;
    short* x_bf    = (short*)(ws);                          // M*K*2        = 8388608
    short* Wt_attn = (short*)(ws + 8388608);                // N1*K*2       = 6291456
    short* Wt_proj = (short*)(ws + 14680064);               // C*K*2        = 2097152
    short* qk      = (short*)(ws + 16777216);               // M*2048*2     = 16777216
    short* vt      = (short*)(ws + 33554432);               // B*1024*T*2   = 8388608
    short* yatt    = (short*)(ws + 41943040);               // M*C*2        = 8388608

    cvt_bf16<<<dim3(M * K / (256 * 8)), 256, 0, stream>>>(x, x_bf, M * K);
    transpose_w<<<dim3(K / 64, N1 / 64), 256, 0, stream>>>(W_attn, Wt_attn, K, N1);
    transpose_w<<<dim3(K / 64, C / 64), 256, 0, stream>>>(W_proj, Wt_proj, K, C);

    gemm_bt<1><<<dim3(M / 128, N1 / 128), 256, 0, stream>>>(x_bf, Wt_attn, b_attn, qk, vt, M, N1, K);
    attn_kernel<<<dim3(2048), 64, 0, stream>>>(qk, vt, yatt);
    gemm_bt<0><<<dim3(M / 128, C / 128), 256, 0, stream>>>(yatt, Wt_proj, b_proj, out, nullptr, M, C, C);
}